// Round 11
// baseline (395.548 us; speedup 1.0000x reference)
//
#include <hip/hip_runtime.h>
#include <hip/hip_bf16.h>

// PRNN R10b: GRU(NH=128, T=32) + MLP head, B=16384.
// = R10 (P5 removed from loop: P4 C-frag -> register fmas vs w2 slice ->
// atomicAdd into lds_logit; one-shot softmax epilogue; lds_hid deleted)
// with the pk2 compile fix (scalar f2bf pair instead of bit_cast of bf162).

#define NSTEP 32
#define BT    16
#define BLK   512

using s8v = __attribute__((ext_vector_type(8))) short;   // 8 bf16
using f4v = __attribute__((ext_vector_type(4))) float;   // MFMA acc

#define L2E 1.4426950408889634f
#define LN2 0.6931471805599453f

__device__ __forceinline__ unsigned short f2bf(float f) {
  __hip_bfloat16 h = __float2bfloat16(f);
  return __builtin_bit_cast(unsigned short, h);
}
__device__ __forceinline__ unsigned pk2(float a, float b) {
  return (unsigned)f2bf(a) | ((unsigned)f2bf(b) << 16);
}
__device__ __forceinline__ s8v pack8s(float sc, float4 u, float4 v) {
  s8v a;
  a[0]=(short)f2bf(sc*u.x); a[1]=(short)f2bf(sc*u.y); a[2]=(short)f2bf(sc*u.z); a[3]=(short)f2bf(sc*u.w);
  a[4]=(short)f2bf(sc*v.x); a[5]=(short)f2bf(sc*v.y); a[6]=(short)f2bf(sc*v.z); a[7]=(short)f2bf(sc*v.w);
  return a;
}
__device__ __forceinline__ f4v mfma16(s8v a, s8v b, f4v c) {
  return __builtin_amdgcn_mfma_f32_16x16x32_bf16(a, b, c, 0, 0, 0);
}
__device__ __forceinline__ float sigm2(float x) {    // arg pre-scaled by L2E
  return __builtin_amdgcn_rcpf(1.f + __builtin_amdgcn_exp2f(-x));
}
__device__ __forceinline__ float tanh2(float x) {    // arg pre-scaled by 2*L2E
  return __builtin_fmaf(2.f, __builtin_amdgcn_rcpf(1.f + __builtin_amdgcn_exp2f(-x)), -1.f);
}

// ---- prep: pack w1 (32 KB) A-frags into d_ws ----
__global__ void prep_kernel(const float* __restrict__ w1, unsigned char* __restrict__ ws) {
  const int task = blockIdx.x;       // 0..31: [mt(8)][ks(4)]
  const int l = threadIdx.x;         // 0..63
  const int mt = task >> 2, ks = task & 3;
  const float* src = w1 + (16*mt + (l & 15)) * 128 + ks*32 + (l >> 4)*8;
  *(s8v*)(ws + (task*64 + l)*16) = pack8s(1.f, *(const float4*)src, *(const float4*)(src + 4));
}

__global__ __launch_bounds__(BLK, 4) void prnn_kernel(
    const float* __restrict__ x, const float* __restrict__ w_ih,
    const float* __restrict__ w_hh, const float* __restrict__ b_ih,
    const float* __restrict__ b_hh, const float* __restrict__ b1,
    const float* __restrict__ w2, const float* __restrict__ b2,
    const unsigned char* __restrict__ ws, float* __restrict__ out) {

  __shared__ __align__(16) unsigned char lds_h[2][4*64*16];   // 8 KB  h B-frags (dbuf)
  __shared__ __align__(16) float lds_logit[NSTEP][4][16];     // 8 KB  partial logits
  __shared__ __align__(16) float lds_xrz[64*4*4];             // 4 KB  xi r,z (*L2E)
  __shared__ __align__(16) float lds_xn[32*4*4];              // 2 KB  xi n (*2L2E)
  __shared__ __align__(16) float lds_bb[256];                 // 1 KB  bhn*2L2E | b1
  __shared__ __align__(16) float lds_b2[4];
  __shared__ unsigned lds_idx[16*8];                          // 0.5 KB
  __shared__ float lds_lp2[NSTEP][16];                        // 2 KB

  const int tid = threadIdx.x;
  const int bbase = blockIdx.x * BT;
  const int lane = tid & 63;
  const int lg = lane >> 4, ln = lane & 15;
  const int w = __builtin_amdgcn_readfirstlane(tid >> 6);   // wave 0..7

  // ---- init: zero logit accumulator (atomicAdd target) ----
  {
    float4* lz = (float4*)&lds_logit[0][0][0];
    lz[tid] = float4{0.f, 0.f, 0.f, 0.f};                   // 512*16B = 8KB
  }
  // ---- init: patch indices (16 seqs x 8 u32) ----
  if (tid < 128) {
    int b = tid >> 3, ch = tid & 7;
    const float* xp = x + (size_t)(bbase + b) * 64 + ch * 8;
    float4 v0 = *(const float4*)xp, v1 = *(const float4*)(xp + 4);
    unsigned pk = ((v0.x!=0.f?1u:0u) | (v0.y!=0.f?2u:0u))
               | (((v0.z!=0.f?1u:0u) | (v0.w!=0.f?2u:0u)) << 8)
               | (((v1.x!=0.f?1u:0u) | (v1.y!=0.f?2u:0u)) << 16)
               | (((v1.z!=0.f?1u:0u) | (v1.w!=0.f?2u:0u)) << 24);
    lds_idx[b*8 + ch] = pk;
  }
  // ---- init: xi tables (prescaled to exp2 domain) ----
  if (tid < 256) {                              // rows 0..255 (r,z) * L2E
    int j = tid;
    float base = b_ih[j] + b_hh[j];
    float wa = w_ih[2*j], wb = w_ih[2*j+1];
    int qq = j >> 2, e = j & 3;
    #pragma unroll
    for (int v = 0; v < 4; ++v)
      lds_xrz[(qq*4+v)*4 + e] = L2E * (base + ((v&1) ? wa : 0.f) + ((v&2) ? wb : 0.f));
  }
  if (tid < 128) {                              // rows 256..383 (n) * 2L2E
    int j2 = 256 + tid;
    float bn = b_ih[j2];
    float wan = w_ih[2*j2], wbn = w_ih[2*j2+1];
    int qn = tid >> 2, en = tid & 3;
    #pragma unroll
    for (int v = 0; v < 4; ++v)
      lds_xn[(qn*4+v)*4 + en] = (2.f*L2E) * (bn + ((v&1) ? wan : 0.f) + ((v&2) ? wbn : 0.f));
  }
  if (tid < 128) lds_bb[tid] = (2.f*L2E) * b_hh[256 + tid];
  else if (tid < 256) lds_bb[tid] = b1[tid - 128];
  if (tid < 4) lds_b2[tid] = b2[tid];

  // ---- register weights: w_hh r/z/n A-frags for this wave's 16-row slice ----
  s8v Ar[4], Az[4], An[4];
  {
    const int row = 16*w + ln;
    #pragma unroll
    for (int ks = 0; ks < 4; ++ks) {
      const float* s0 = w_hh + row*128 + ks*32 + lg*8;
      Ar[ks] = pack8s(L2E, *(const float4*)s0, *(const float4*)(s0 + 4));
      const float* s1 = s0 + 128*128;
      Az[ks] = pack8s(L2E, *(const float4*)s1, *(const float4*)(s1 + 4));
      const float* s2 = s0 + 256*128;
      An[ks] = pack8s(2.f*L2E, *(const float4*)s2, *(const float4*)(s2 + 4));
    }
  }
  // ---- per-lane w2 slice: w2[c][16w + 4lg + r], 16 regs ----
  float w2t[4][4];
  {
    const int rbase = 16*w + 4*lg;
    #pragma unroll
    for (int c = 0; c < 4; ++c) {
      const f4v v = *(const f4v*)(w2 + c*128 + rbase);
      w2t[c][0]=v[0]; w2t[c][1]=v[1]; w2t[c][2]=v[2]; w2t[c][3]=v[3];
    }
  }
  const int q = 4*w + lg;
  const s8v* __restrict__ wsf = (const s8v*)ws;   // w1 frags

  __syncthreads();

  // ---- per-lane packed patch history for batch col ln (2 bits/step) ----
  unsigned pk0a = 0, pk0b = 0;
  #pragma unroll
  for (int w8 = 0; w8 < 4; ++w8) {
    unsigned u = lds_idx[ln*8 + w8];
    pk0a |= (((u&3u) | ((u>>6)&0xCu) | ((u>>12)&0x30u) | ((u>>18)&0xC0u)) << (8*w8));
    unsigned u2 = lds_idx[ln*8 + 4 + w8];
    pk0b |= (((u2&3u) | ((u2>>6)&0xCu) | ((u2>>12)&0x30u) | ((u2>>18)&0xC0u)) << (8*w8));
  }

  // C-frag -> B-frag write offset (h)
  const unsigned wroff =
      (unsigned)((((w>>1)*64 + 16*(2*(w&1) + (lg>>1)) + ln)*16) + 8*(lg&1));

  s8v Bf[4];
  #pragma unroll
  for (int ks = 0; ks < 4; ++ks)
    #pragma unroll
    for (int e = 0; e < 8; ++e) Bf[ks][e] = (short)0;
  f4v hfr;
  hfr[0]=0.f; hfr[1]=0.f; hfr[2]=0.f; hfr[3]=0.f;
  int pv0 = 0;

  #pragma unroll 1
  for (int tt = 0; tt < NSTEP; tt += 2) {
    #pragma unroll
    for (int k = 0; k < 2; ++k) {          // slot-specialized (addresses hoistable)
      const int t = tt + k;
      const int slot = k;
      // ---- Phase A: gate MFMAs (C-init = prescaled xi) + gates + h write ----
      {
        const int var = pv0;
        f4v aR = *(const f4v*)&lds_xrz[(q*4 + var)*4];
        f4v aZ = *(const f4v*)&lds_xrz[((q+32)*4 + var)*4];
        f4v aN = *(const f4v*)&lds_bb[q*4];
        #pragma unroll
        for (int ks = 0; ks < 4; ++ks) {
          aR = mfma16(Ar[ks], Bf[ks], aR);
          aZ = mfma16(Az[ks], Bf[ks], aZ);
          aN = mfma16(An[ks], Bf[ks], aN);
        }
        const f4v xnv = *(const f4v*)&lds_xn[(q*4 + var)*4];
        f4v hn;
        #pragma unroll
        for (int r = 0; r < 4; ++r) {
          float R  = sigm2(aR[r]);
          float Z  = sigm2(aZ[r]);
          float Ng = tanh2(__builtin_fmaf(R, aN[r], xnv[r]));
          hn[r] = __builtin_fmaf(Z, hfr[r] - Ng, Ng);
        }
        hfr = hn;
        uint2 wv;
        wv.x = pk2(hn[0], hn[1]);
        wv.y = pk2(hn[2], hn[3]);
        *(uint2*)(&lds_h[slot][wroff]) = wv;
      }
      __syncthreads();                     // the ONLY barrier per step
      // ---- Phase B: Bf reload (feeds P1 of t+1 and P4 now) ----
      #pragma unroll
      for (int ks = 0; ks < 4; ++ks)
        Bf[ks] = *(const s8v*)(&lds_h[slot][(ks*64 + lane)*16]);
      // ---- P4: hid C-frag = relu(W1 h + b1); fold into partial logits ----
      {
        f4v hc = *(const f4v*)&lds_bb[128 + q*4];
        #pragma unroll
        for (int ks = 0; ks < 4; ++ks)
          hc = mfma16(wsf[(w*4 + ks)*64 + lane], Bf[ks], hc);
        const float h0 = fmaxf(hc[0], 0.f), h1 = fmaxf(hc[1], 0.f);
        const float h2 = fmaxf(hc[2], 0.f), h3 = fmaxf(hc[3], 0.f);
        #pragma unroll
        for (int c = 0; c < 4; ++c) {
          float p = w2t[c][0]*h0;
          p = __builtin_fmaf(w2t[c][1], h1, p);
          p = __builtin_fmaf(w2t[c][2], h2, p);
          p = __builtin_fmaf(w2t[c][3], h3, p);
          atomicAdd(&lds_logit[t][c][ln], p);
        }
      }
      // ---- teacher-forcing input for step t+1 ----
      pv0 = (int)((((t & 16) ? pk0b : pk0a) >> ((2*t) & 31)) & 3);
    }
  }

  __syncthreads();                         // all logit atomics complete

  // ---- epilogue: one (seq, step) per thread ----
  {
    const int s = tid & 15, t2 = tid >> 4;
    const float l0 = lds_logit[t2][0][s] + lds_b2[0];
    const float l1 = lds_logit[t2][1][s] + lds_b2[1];
    const float l2 = lds_logit[t2][2][s] + lds_b2[2];
    const float l3 = lds_logit[t2][3][s] + lds_b2[3];
    const int ic = (int)((lds_idx[s*8 + (t2 >> 2)] >> (8*(t2 & 3))) & 3);
    const float m = fmaxf(fmaxf(l0, l1), fmaxf(l2, l3));
    const float sum = __builtin_amdgcn_exp2f((l0-m)*L2E) + __builtin_amdgcn_exp2f((l1-m)*L2E)
                    + __builtin_amdgcn_exp2f((l2-m)*L2E) + __builtin_amdgcn_exp2f((l3-m)*L2E);
    const float sel = (ic == 0) ? l0 : (ic == 1) ? l1 : (ic == 2) ? l2 : l3;
    lds_lp2[t2][s] = (sel - m) - __builtin_amdgcn_logf(sum) * LN2;
  }
  __syncthreads();
  if (tid < 16) {
    float s = 0.f;
    #pragma unroll
    for (int t2 = 0; t2 < NSTEP; ++t2) s += lds_lp2[t2][tid];
    out[bbase + tid] = s;
  }
}

extern "C" void kernel_launch(void* const* d_in, const int* in_sizes, int n_in,
                              void* d_out, int out_size, void* d_ws, size_t ws_size,
                              hipStream_t stream) {
  const float* x    = (const float*)d_in[0];
  const float* w_ih = (const float*)d_in[1];
  const float* w_hh = (const float*)d_in[2];
  const float* b_ih = (const float*)d_in[3];
  const float* b_hh = (const float*)d_in[4];
  const float* w1   = (const float*)d_in[5];
  const float* b1   = (const float*)d_in[6];
  const float* w2   = (const float*)d_in[7];
  const float* b2   = (const float*)d_in[8];
  float* out = (float*)d_out;
  unsigned char* ws = (unsigned char*)d_ws;      // needs 32 KB

  prep_kernel<<<32, 64, 0, stream>>>(w1, ws);

  int B = in_sizes[0] / 64;          // 16384
  int grid = B / BT;                 // 1024
  prnn_kernel<<<grid, BLK, 0, stream>>>(x, w_ih, w_hh, b_ih, b_hh, b1, w2, b2, ws, out);
}